// Round 2
// baseline (736.258 us; speedup 1.0000x reference)
//
#include <hip/hip_runtime.h>
#include <stdint.h>

#define N_NODES 100000
#define N_EDGES 1600000
#define IN_DIM 256
#define HID_DIM 128
#define OUT_DIM 128

typedef __attribute__((ext_vector_type(8))) short short8;
typedef __attribute__((ext_vector_type(4))) float floatx4;

__device__ __forceinline__ float bf2f(unsigned short u) {
    union { unsigned int i; float f; } v; v.i = ((unsigned int)u) << 16; return v.f;
}
__device__ __forceinline__ unsigned short f2bf(float f) {
    union { float fl; unsigned int i; } v; v.fl = f;
    unsigned int x = v.i;
    return (unsigned short)((x + 0x7fffu + ((x >> 16) & 1u)) >> 16);
}
__device__ __forceinline__ float bflo(unsigned int u) {
    union { unsigned int i; float f; } v; v.i = u << 16; return v.f;
}
__device__ __forceinline__ float bfhi(unsigned int u) {
    union { unsigned int i; float f; } v; v.i = u & 0xffff0000u; return v.f;
}

// Runtime input-dtype probes (wave-uniform flags in ws):
// flags[0] = 1 if float tensors are f32 (else bf16); flags[1] = 1 if indices are i64 (else i32).
__global__ void k_detect(const unsigned int* __restrict__ xu, const unsigned int* __restrict__ eu,
                         int* __restrict__ flags) {
    __shared__ int s_huge, s_odd;
    if (threadIdx.x == 0) { s_huge = 0; s_odd = 0; }
    __syncthreads();
    int huge = 0, odd = 0;
    for (int i = threadIdx.x; i < 1024; i += 256) {
        unsigned int b = xu[i];
        unsigned int e = (b >> 23) & 0xffu;
        if (e >= 0xf0u) huge = 1;           // bf16-pair reinterpreted as f32 → astronomically large exp
        if (eu[2 * i + 1] != 0) odd = 1;    // int64 hi-words are all zero for non-negative idx
    }
    if (huge) atomicOr(&s_huge, 1);
    if (odd) atomicOr(&s_odd, 1);
    __syncthreads();
    if (threadIdx.x == 0) { flags[0] = s_huge ? 0 : 1; flags[1] = s_odd ? 0 : 1; }
}

__device__ __forceinline__ int load_idx(const void* base, long long i, int i64m) {
    int v = i64m ? (int)((const long long*)base)[i] : ((const int*)base)[i];
    return v < 0 ? 0 : (v >= N_NODES ? N_NODES - 1 : v);  // clamp: clean fail, never fault
}
__device__ __forceinline__ float load_f(const void* base, long long i, int f32m) {
    return f32m ? ((const float*)base)[i] : bf2f(((const unsigned short*)base)[i]);
}

// ---------------- degree / dinv ----------------
__global__ void k_init(float* deg, int* cnt, int n) {
    int i = blockIdx.x * 256 + threadIdx.x;
    if (i < n) { deg[i] = 1.0f; cnt[i] = 0; }  // self-loop weight 1
}

__global__ void k_deg_count(const void* __restrict__ ei, const void* __restrict__ ew,
                            const int* __restrict__ flags, float* deg, int* cnt, int e) {
    int i = blockIdx.x * 256 + threadIdx.x;
    int f32m = flags[0], i64m = flags[1];
    if (i < e) {
        int d = load_idx(ei, (long long)N_EDGES + i, i64m);
        atomicAdd(&deg[d], load_f(ew, i, f32m));
        atomicAdd(&cnt[d], 1);
    }
}

__global__ void k_dinv(const float* __restrict__ deg, float* __restrict__ dinv, int n) {
    int i = blockIdx.x * 256 + threadIdx.x;
    if (i < n) {
        float d = deg[i];
        dinv[i] = d > 0.0f ? rsqrtf(d) : 0.0f;
    }
}

// ---------------- CSR build: 3-kernel scan + scatter ----------------
#define SCAN_CHUNK 1024

__global__ void k_scan1(const int* __restrict__ cnt, int* __restrict__ bsum, int n) {
    __shared__ int lds[256];
    int t = threadIdx.x;
    int base = blockIdx.x * SCAN_CHUNK + t * 4;
    int s = 0;
#pragma unroll
    for (int j = 0; j < 4; j++) { int i = base + j; if (i < n) s += cnt[i]; }
    lds[t] = s; __syncthreads();
    for (int off = 128; off > 0; off >>= 1) {
        if (t < off) lds[t] += lds[t + off];
        __syncthreads();
    }
    if (t == 0) bsum[blockIdx.x] = lds[0];
}

__global__ void k_scan2(const int* __restrict__ bsum, int* __restrict__ boff, int nb,
                        int* __restrict__ rowptr, int n) {
    if (threadIdx.x == 0 && blockIdx.x == 0) {
        int run = 0;
        for (int b = 0; b < nb; b++) { boff[b] = run; run += bsum[b]; }
        rowptr[n] = run;
    }
}

__global__ void k_scan3(const int* __restrict__ cnt, const int* __restrict__ boff,
                        int* __restrict__ rowptr, int* __restrict__ cursor, int n) {
    __shared__ int lds[256];
    int t = threadIdx.x;
    int base = blockIdx.x * SCAN_CHUNK + t * 4;
    int v[4]; int s = 0;
#pragma unroll
    for (int j = 0; j < 4; j++) { int i = base + j; v[j] = (i < n) ? cnt[i] : 0; s += v[j]; }
    lds[t] = s; __syncthreads();
    for (int off = 1; off < 256; off <<= 1) {
        int x = 0;
        if (t >= off) x = lds[t - off];
        __syncthreads();
        lds[t] += x;
        __syncthreads();
    }
    int excl = lds[t] - s + boff[blockIdx.x];
#pragma unroll
    for (int j = 0; j < 4; j++) {
        int i = base + j;
        if (i < n) { rowptr[i] = excl; cursor[i] = excl; excl += v[j]; }
    }
}

__global__ void k_scatter(const void* __restrict__ ei, const void* __restrict__ ew,
                          const int* __restrict__ flags, const float* __restrict__ dinv,
                          int* cursor, int* __restrict__ csr_src, float* __restrict__ csr_norm,
                          int e) {
    int i = blockIdx.x * 256 + threadIdx.x;
    int f32m = flags[0], i64m = flags[1];
    if (i < e) {
        int s = load_idx(ei, i, i64m);
        int d = load_idx(ei, (long long)N_EDGES + i, i64m);
        float norm = dinv[s] * load_f(ew, i, f32m) * dinv[d];
        int p = atomicAdd(&cursor[d], 1);
        csr_src[p] = s;
        csr_norm[p] = norm;
    }
}

// ---------------- weight transpose → bf16 (contiguous B-fragment loads) ----------------
__global__ void k_transpose(const void* __restrict__ W1, const void* __restrict__ W2,
                            const int* __restrict__ flags,
                            unsigned short* __restrict__ W1T, unsigned short* __restrict__ W2T) {
    int i = blockIdx.x * 256 + threadIdx.x;
    int f32m = flags[0];
    if (i < IN_DIM * HID_DIM) {
        int k = i / HID_DIM, n = i % HID_DIM;
        W1T[n * IN_DIM + k] = f2bf(load_f(W1, i, f32m));
    } else {
        int j = i - IN_DIM * HID_DIM;
        if (j < HID_DIM * OUT_DIM) {
            int k = j / OUT_DIM, n = j % OUT_DIM;
            W2T[n * HID_DIM + k] = f2bf(load_f(W2, j, f32m));
        }
    }
}

// ---------------- GEMM: H[n,128] = A[n,K] @ W[K,128], MFMA 16x16x32 bf16 ----------------
// Wave: 16 rows x 128 cols (8 col tiles). A-frag row=lane&15, k=quad*8+j; B-frag col=lane&15
// from W^T; D: col=lane&15, row=quad*4+reg. RAWA: A is a raw input (f32 or bf16 per flag),
// else A is internal bf16.
template <int K, bool RAWA>
__global__ void k_gemm(const void* __restrict__ A, const unsigned short* __restrict__ WT,
                       unsigned short* __restrict__ H, const int* __restrict__ flags, int n) {
    int wave = threadIdx.x >> 6;
    int lane = threadIdx.x & 63;
    int quad = lane >> 4;
    int l16 = lane & 15;
    int rowbase = blockIdx.x * 64 + wave * 16;
    int arow = rowbase + l16;
    if (arow >= n) arow = n - 1;  // clamp loads; stores guarded below
    int f32m = RAWA ? flags[0] : 0;

    floatx4 acc[8];
#pragma unroll
    for (int c = 0; c < 8; c++) acc[c] = (floatx4){0.f, 0.f, 0.f, 0.f};

#pragma unroll
    for (int k0 = 0; k0 < K; k0 += 32) {
        short8 af;
        if (RAWA && f32m) {
            const float* ap = (const float*)A + (size_t)arow * K + quad * 8 + k0;
            float4 u0 = *(const float4*)ap;
            float4 u1 = *(const float4*)(ap + 4);
            af[0] = (short)f2bf(u0.x); af[1] = (short)f2bf(u0.y);
            af[2] = (short)f2bf(u0.z); af[3] = (short)f2bf(u0.w);
            af[4] = (short)f2bf(u1.x); af[5] = (short)f2bf(u1.y);
            af[6] = (short)f2bf(u1.z); af[7] = (short)f2bf(u1.w);
        } else {
            af = *(const short8*)((const unsigned short*)A + (size_t)arow * K + quad * 8 + k0);
        }
#pragma unroll
        for (int c = 0; c < 8; c++) {
            const unsigned short* bptr = WT + (size_t)(c * 16 + l16) * K + k0 + quad * 8;
            short8 bf = *(const short8*)bptr;
            acc[c] = __builtin_amdgcn_mfma_f32_16x16x32_bf16(af, bf, acc[c], 0, 0, 0);
        }
    }

#pragma unroll
    for (int c = 0; c < 8; c++) {
#pragma unroll
        for (int r = 0; r < 4; r++) {
            int grow = rowbase + quad * 4 + r;
            if (grow < n) H[(size_t)grow * 128 + c * 16 + l16] = f2bf(acc[c][r]);
        }
    }
}

// ---------------- aggregation: out[n] = sum_in norm*h[src] + dinv[n]^2*h[n] + b (opt ReLU) ----
// 256 thr = 8 nodes x 32 lanes; lane covers 4 consecutive cols. FINAL: write d_out in input
// float dtype; else write internal bf16.
template <bool RELU, bool FINAL>
__global__ void k_aggregate(const unsigned short* __restrict__ H, const int* __restrict__ rowptr,
                            const int* __restrict__ csr_src, const float* __restrict__ csr_norm,
                            const float* __restrict__ dinv, const void* __restrict__ bias,
                            void* __restrict__ out, const int* __restrict__ flags, int n) {
    int node = blockIdx.x * 8 + (threadIdx.x >> 5);
    int lane = threadIdx.x & 31;
    if (node >= n) return;
    int col = lane * 4;
    int f32m = flags[0];

    float a0 = load_f(bias, col, f32m),     a1 = load_f(bias, col + 1, f32m);
    float a2 = load_f(bias, col + 2, f32m), a3 = load_f(bias, col + 3, f32m);

    float s = dinv[node];
    float coef = s * s;
    uint2 u = *(const uint2*)(H + (size_t)node * 128 + col);
    a0 += coef * bflo(u.x); a1 += coef * bfhi(u.x);
    a2 += coef * bflo(u.y); a3 += coef * bfhi(u.y);

    int e0 = rowptr[node], e1 = rowptr[node + 1];
    for (int e = e0; e < e1; e++) {
        int src = csr_src[e];
        float w = csr_norm[e];
        uint2 hu = *(const uint2*)(H + (size_t)src * 128 + col);
        a0 += w * bflo(hu.x); a1 += w * bfhi(hu.x);
        a2 += w * bflo(hu.y); a3 += w * bfhi(hu.y);
    }
    if (RELU) {
        a0 = fmaxf(a0, 0.f); a1 = fmaxf(a1, 0.f);
        a2 = fmaxf(a2, 0.f); a3 = fmaxf(a3, 0.f);
    }
    if (FINAL && f32m) {
        float4 o = {a0, a1, a2, a3};
        *(float4*)((float*)out + (size_t)node * 128 + col) = o;
    } else {
        uint2 o;
        o.x = (unsigned int)f2bf(a0) | ((unsigned int)f2bf(a1) << 16);
        o.y = (unsigned int)f2bf(a2) | ((unsigned int)f2bf(a3) << 16);
        *(uint2*)((unsigned short*)out + (size_t)node * 128 + col) = o;
    }
}

extern "C" void kernel_launch(void* const* d_in, const int* in_sizes, int n_in,
                              void* d_out, int out_size, void* d_ws, size_t ws_size,
                              hipStream_t stream) {
    const void* x  = d_in[0];
    const void* ei = d_in[1];
    const void* ew = d_in[2];
    const void* W1 = d_in[3];
    const void* b1 = d_in[4];
    const void* W2 = d_in[5];
    const void* b2 = d_in[6];

    char* p = (char*)d_ws;
    auto alloc = [&](size_t bytes) { char* r = p; p += (bytes + 255) & ~(size_t)255; return r; };
    int*   flags    = (int*)alloc(256);
    float* deg      = (float*)alloc((size_t)N_NODES * 4);
    float* dinv     = (float*)alloc((size_t)N_NODES * 4);
    int*   cnt      = (int*)alloc((size_t)N_NODES * 4);
    int*   rowptr   = (int*)alloc((size_t)(N_NODES + 1) * 4);
    int*   cursor   = (int*)alloc((size_t)N_NODES * 4);
    int*   bsum     = (int*)alloc(256 * 4);
    int*   boff     = (int*)alloc(256 * 4);
    int*   csr_src  = (int*)alloc((size_t)N_EDGES * 4);
    float* csr_norm = (float*)alloc((size_t)N_EDGES * 4);
    unsigned short* W1T  = (unsigned short*)alloc((size_t)IN_DIM * HID_DIM * 2);
    unsigned short* W2T  = (unsigned short*)alloc((size_t)HID_DIM * OUT_DIM * 2);
    unsigned short* hbuf = (unsigned short*)alloc((size_t)N_NODES * 128 * 2);
    unsigned short* zbuf = (unsigned short*)alloc((size_t)N_NODES * 128 * 2);

    int nbN = (N_NODES + 255) / 256;
    int nbE = (N_EDGES + 255) / 256;
    int nsb = (N_NODES + SCAN_CHUNK - 1) / SCAN_CHUNK;  // 98

    k_detect<<<1, 256, 0, stream>>>((const unsigned int*)x, (const unsigned int*)ei, flags);
    k_init<<<nbN, 256, 0, stream>>>(deg, cnt, N_NODES);
    k_deg_count<<<nbE, 256, 0, stream>>>(ei, ew, flags, deg, cnt, N_EDGES);
    k_dinv<<<nbN, 256, 0, stream>>>(deg, dinv, N_NODES);
    k_scan1<<<nsb, 256, 0, stream>>>(cnt, bsum, N_NODES);
    k_scan2<<<1, 64, 0, stream>>>(bsum, boff, nsb, rowptr, N_NODES);
    k_scan3<<<nsb, 256, 0, stream>>>(cnt, boff, rowptr, cursor, N_NODES);
    k_scatter<<<nbE, 256, 0, stream>>>(ei, ew, flags, dinv, cursor, csr_src, csr_norm, N_EDGES);
    k_transpose<<<(IN_DIM * HID_DIM + HID_DIM * OUT_DIM + 255) / 256, 256, 0, stream>>>(W1, W2, flags, W1T, W2T);

    k_gemm<IN_DIM, true><<<(N_NODES + 63) / 64, 256, 0, stream>>>(x, W1T, hbuf, flags, N_NODES);
    k_aggregate<true, false><<<(N_NODES + 7) / 8, 256, 0, stream>>>(hbuf, rowptr, csr_src, csr_norm,
                                                                    dinv, b1, zbuf, flags, N_NODES);
    k_gemm<HID_DIM, false><<<(N_NODES + 63) / 64, 256, 0, stream>>>(zbuf, W2T, hbuf, flags, N_NODES);
    k_aggregate<false, true><<<(N_NODES + 7) / 8, 256, 0, stream>>>(hbuf, rowptr, csr_src, csr_norm,
                                                                    dinv, b2, d_out, flags, N_NODES);
}

// Round 3
// 619.100 us; speedup vs baseline: 1.1892x; 1.1892x over previous
//
#include <hip/hip_runtime.h>
#include <stdint.h>

#define N_NODES 100000
#define N_EDGES 1600000
#define IN_DIM 256
#define HID_DIM 128
#define OUT_DIM 128

typedef __attribute__((ext_vector_type(8))) short short8;
typedef __attribute__((ext_vector_type(4))) float floatx4;

__device__ __forceinline__ float bf2f(unsigned short u) {
    union { unsigned int i; float f; } v; v.i = ((unsigned int)u) << 16; return v.f;
}
__device__ __forceinline__ unsigned short f2bf(float f) {
    union { float fl; unsigned int i; } v; v.fl = f;
    unsigned int x = v.i;
    return (unsigned short)((x + 0x7fffu + ((x >> 16) & 1u)) >> 16);
}
__device__ __forceinline__ float bflo(unsigned int u) {
    union { unsigned int i; float f; } v; v.i = u << 16; return v.f;
}
__device__ __forceinline__ float bfhi(unsigned int u) {
    union { unsigned int i; float f; } v; v.i = u & 0xffff0000u; return v.f;
}
__device__ __forceinline__ float asf(unsigned int u) {
    union { unsigned int i; float f; } v; v.i = u; return v.f;
}
__device__ __forceinline__ unsigned int asu(float f) {
    union { float fl; unsigned int i; } v; v.fl = f; return v.i;
}

// Runtime input-dtype probes: flags[0]=1 if floats are f32 (else bf16); flags[1]=1 if idx i64.
__global__ void k_detect(const unsigned int* __restrict__ xu, const unsigned int* __restrict__ eu,
                         int* __restrict__ flags) {
    __shared__ int s_huge, s_odd;
    if (threadIdx.x == 0) { s_huge = 0; s_odd = 0; }
    __syncthreads();
    int huge = 0, odd = 0;
    for (int i = threadIdx.x; i < 1024; i += 256) {
        unsigned int b = xu[i];
        unsigned int e = (b >> 23) & 0xffu;
        if (e >= 0xf0u) huge = 1;           // bf16-pair reinterpreted as f32 → huge exponent
        if (eu[2 * i + 1] != 0) odd = 1;    // i64 hi-words all zero for non-negative idx
    }
    if (huge) atomicOr(&s_huge, 1);
    if (odd) atomicOr(&s_odd, 1);
    __syncthreads();
    if (threadIdx.x == 0) { flags[0] = s_huge ? 0 : 1; flags[1] = s_odd ? 0 : 1; }
}

__device__ __forceinline__ int load_idx(const void* base, long long i, int i64m) {
    int v = i64m ? (int)((const long long*)base)[i] : ((const int*)base)[i];
    return v < 0 ? 0 : (v >= N_NODES ? N_NODES - 1 : v);
}
__device__ __forceinline__ float load_f(const void* base, long long i, int f32m) {
    return f32m ? ((const float*)base)[i] : bf2f(((const unsigned short*)base)[i]);
}

// ---------------- histogram (int atomics only) ----------------
__global__ void k_init(int* cnt, int n) {
    int i = blockIdx.x * 256 + threadIdx.x;
    if (i < n) cnt[i] = 0;
}

__global__ void k_cnt(const void* __restrict__ ei, const int* __restrict__ flags,
                      int* cnt, int e) {
    int i = blockIdx.x * 256 + threadIdx.x;
    int i64m = flags[1];
    if (i < e) {
        int d = load_idx(ei, (long long)N_EDGES + i, i64m);
        atomicAdd(&cnt[d], 1);
    }
}

// ---------------- CSR build: 3-kernel scan + scatter ----------------
#define SCAN_CHUNK 1024

__global__ void k_scan1(const int* __restrict__ cnt, int* __restrict__ bsum, int n) {
    __shared__ int lds[256];
    int t = threadIdx.x;
    int base = blockIdx.x * SCAN_CHUNK + t * 4;
    int s = 0;
#pragma unroll
    for (int j = 0; j < 4; j++) { int i = base + j; if (i < n) s += cnt[i]; }
    lds[t] = s; __syncthreads();
    for (int off = 128; off > 0; off >>= 1) {
        if (t < off) lds[t] += lds[t + off];
        __syncthreads();
    }
    if (t == 0) bsum[blockIdx.x] = lds[0];
}

__global__ void k_scan2(const int* __restrict__ bsum, int* __restrict__ boff, int nb,
                        int* __restrict__ rowptr, int n) {
    if (threadIdx.x == 0 && blockIdx.x == 0) {
        int run = 0;
        for (int b = 0; b < nb; b++) { boff[b] = run; run += bsum[b]; }
        rowptr[n] = run;
    }
}

__global__ void k_scan3(const int* __restrict__ cnt, const int* __restrict__ boff,
                        int* __restrict__ rowptr, int* __restrict__ cursor, int n) {
    __shared__ int lds[256];
    int t = threadIdx.x;
    int base = blockIdx.x * SCAN_CHUNK + t * 4;
    int v[4]; int s = 0;
#pragma unroll
    for (int j = 0; j < 4; j++) { int i = base + j; v[j] = (i < n) ? cnt[i] : 0; s += v[j]; }
    lds[t] = s; __syncthreads();
    for (int off = 1; off < 256; off <<= 1) {
        int x = 0;
        if (t >= off) x = lds[t - off];
        __syncthreads();
        lds[t] += x;
        __syncthreads();
    }
    int excl = lds[t] - s + boff[blockIdx.x];
#pragma unroll
    for (int j = 0; j < 4; j++) {
        int i = base + j;
        if (i < n) { rowptr[i] = excl; cursor[i] = excl; excl += v[j]; }
    }
}

// scatter (src, w) — norm factorized: dinv[dst] applied in aggregate, dinv[src] in k_norm
__global__ void k_scatter(const void* __restrict__ ei, const void* __restrict__ ew,
                          const int* __restrict__ flags,
                          int* cursor, uint2* __restrict__ csr, int e) {
    int i = blockIdx.x * 256 + threadIdx.x;
    int f32m = flags[0], i64m = flags[1];
    if (i < e) {
        int s = load_idx(ei, i, i64m);
        int d = load_idx(ei, (long long)N_EDGES + i, i64m);
        float w = load_f(ew, i, f32m);
        int p = atomicAdd(&cursor[d], 1);
        uint2 c; c.x = (unsigned int)s; c.y = asu(w);
        csr[p] = c;
    }
}

// per-node: deg = 1 + sum(w) over CSR range; dinv = rsqrt(deg). No atomics.
__global__ void k_degnorm(const uint2* __restrict__ csr, const int* __restrict__ rowptr,
                          float* __restrict__ dinv, int n) {
    int i = blockIdx.x * 256 + threadIdx.x;
    if (i < n) {
        int e0 = rowptr[i], e1 = rowptr[i + 1];
        float s = 1.0f;  // self-loop
        for (int e = e0; e < e1; e++) s += asf(csr[e].y);
        dinv[i] = rsqrtf(s);
    }
}

// per-edge: w *= dinv[src]  (coalesced; dinv table is 400KB, L2-resident)
__global__ void k_norm(uint2* __restrict__ csr, const float* __restrict__ dinv, int e) {
    int i = blockIdx.x * 256 + threadIdx.x;
    if (i < e) {
        uint2 c = csr[i];
        csr[i].y = asu(asf(c.y) * dinv[c.x]);
    }
}

// ---------------- weight transpose → bf16 ----------------
__global__ void k_transpose(const void* __restrict__ W1, const void* __restrict__ W2,
                            const int* __restrict__ flags,
                            unsigned short* __restrict__ W1T, unsigned short* __restrict__ W2T) {
    int i = blockIdx.x * 256 + threadIdx.x;
    int f32m = flags[0];
    if (i < IN_DIM * HID_DIM) {
        int k = i / HID_DIM, n = i % HID_DIM;
        W1T[n * IN_DIM + k] = f2bf(load_f(W1, i, f32m));
    } else {
        int j = i - IN_DIM * HID_DIM;
        if (j < HID_DIM * OUT_DIM) {
            int k = j / OUT_DIM, n = j % OUT_DIM;
            W2T[n * HID_DIM + k] = f2bf(load_f(W2, j, f32m));
        }
    }
}

// ---------------- GEMM: H[n,128] = A[n,K] @ W[K,128], MFMA 16x16x32 bf16 ----------------
template <int K, bool RAWA>
__global__ void k_gemm(const void* __restrict__ A, const unsigned short* __restrict__ WT,
                       unsigned short* __restrict__ H, const int* __restrict__ flags, int n) {
    int wave = threadIdx.x >> 6;
    int lane = threadIdx.x & 63;
    int quad = lane >> 4;
    int l16 = lane & 15;
    int rowbase = blockIdx.x * 64 + wave * 16;
    int arow = rowbase + l16;
    if (arow >= n) arow = n - 1;
    int f32m = RAWA ? flags[0] : 0;

    floatx4 acc[8];
#pragma unroll
    for (int c = 0; c < 8; c++) acc[c] = (floatx4){0.f, 0.f, 0.f, 0.f};

#pragma unroll
    for (int k0 = 0; k0 < K; k0 += 32) {
        short8 af;
        if (RAWA && f32m) {
            const float* ap = (const float*)A + (size_t)arow * K + quad * 8 + k0;
            float4 u0 = *(const float4*)ap;
            float4 u1 = *(const float4*)(ap + 4);
            af[0] = (short)f2bf(u0.x); af[1] = (short)f2bf(u0.y);
            af[2] = (short)f2bf(u0.z); af[3] = (short)f2bf(u0.w);
            af[4] = (short)f2bf(u1.x); af[5] = (short)f2bf(u1.y);
            af[6] = (short)f2bf(u1.z); af[7] = (short)f2bf(u1.w);
        } else {
            af = *(const short8*)((const unsigned short*)A + (size_t)arow * K + quad * 8 + k0);
        }
#pragma unroll
        for (int c = 0; c < 8; c++) {
            const unsigned short* bptr = WT + (size_t)(c * 16 + l16) * K + k0 + quad * 8;
            short8 bf = *(const short8*)bptr;
            acc[c] = __builtin_amdgcn_mfma_f32_16x16x32_bf16(af, bf, acc[c], 0, 0, 0);
        }
    }

#pragma unroll
    for (int c = 0; c < 8; c++) {
#pragma unroll
        for (int r = 0; r < 4; r++) {
            int grow = rowbase + quad * 4 + r;
            if (grow < n) H[(size_t)grow * 128 + c * 16 + l16] = f2bf(acc[c][r]);
        }
    }
}

// ---------------- aggregation ----------------
// out[n] = dinv[n]*sum_e (dinv[src]*w)*h[src] + dinv[n]^2*h[n] + b   (opt ReLU)
// 8 nodes x 32 lanes per block; lane covers 4 consecutive cols; edge loop unrolled x2.
template <bool RELU, bool FINAL>
__global__ void k_aggregate(const unsigned short* __restrict__ H, const int* __restrict__ rowptr,
                            const uint2* __restrict__ csr, const float* __restrict__ dinv,
                            const void* __restrict__ bias, void* __restrict__ out,
                            const int* __restrict__ flags, int n) {
    int node = blockIdx.x * 8 + (threadIdx.x >> 5);
    int lane = threadIdx.x & 31;
    if (node >= n) return;
    int col = lane * 4;
    int f32m = flags[0];

    float a0 = 0.f, a1 = 0.f, a2 = 0.f, a3 = 0.f;
    int e0 = rowptr[node], e1 = rowptr[node + 1];
    int e = e0;
    for (; e + 2 <= e1; e += 2) {
        uint2 c0 = csr[e], c1 = csr[e + 1];
        uint2 h0 = *(const uint2*)(H + (size_t)c0.x * 128 + col);
        uint2 h1 = *(const uint2*)(H + (size_t)c1.x * 128 + col);
        float w0 = asf(c0.y), w1 = asf(c1.y);
        a0 += w0 * bflo(h0.x); a1 += w0 * bfhi(h0.x);
        a2 += w0 * bflo(h0.y); a3 += w0 * bfhi(h0.y);
        a0 += w1 * bflo(h1.x); a1 += w1 * bfhi(h1.x);
        a2 += w1 * bflo(h1.y); a3 += w1 * bfhi(h1.y);
    }
    if (e < e1) {
        uint2 c0 = csr[e];
        uint2 h0 = *(const uint2*)(H + (size_t)c0.x * 128 + col);
        float w0 = asf(c0.y);
        a0 += w0 * bflo(h0.x); a1 += w0 * bfhi(h0.x);
        a2 += w0 * bflo(h0.y); a3 += w0 * bfhi(h0.y);
    }

    float dn = dinv[node];
    float coef = dn * dn;
    uint2 u = *(const uint2*)(H + (size_t)node * 128 + col);
    a0 = dn * a0 + coef * bflo(u.x) + load_f(bias, col, f32m);
    a1 = dn * a1 + coef * bfhi(u.x) + load_f(bias, col + 1, f32m);
    a2 = dn * a2 + coef * bflo(u.y) + load_f(bias, col + 2, f32m);
    a3 = dn * a3 + coef * bfhi(u.y) + load_f(bias, col + 3, f32m);

    if (RELU) {
        a0 = fmaxf(a0, 0.f); a1 = fmaxf(a1, 0.f);
        a2 = fmaxf(a2, 0.f); a3 = fmaxf(a3, 0.f);
    }
    if (FINAL && f32m) {
        float4 o = {a0, a1, a2, a3};
        *(float4*)((float*)out + (size_t)node * 128 + col) = o;
    } else {
        uint2 o;
        o.x = (unsigned int)f2bf(a0) | ((unsigned int)f2bf(a1) << 16);
        o.y = (unsigned int)f2bf(a2) | ((unsigned int)f2bf(a3) << 16);
        *(uint2*)((unsigned short*)out + (size_t)node * 128 + col) = o;
    }
}

extern "C" void kernel_launch(void* const* d_in, const int* in_sizes, int n_in,
                              void* d_out, int out_size, void* d_ws, size_t ws_size,
                              hipStream_t stream) {
    const void* x  = d_in[0];
    const void* ei = d_in[1];
    const void* ew = d_in[2];
    const void* W1 = d_in[3];
    const void* b1 = d_in[4];
    const void* W2 = d_in[5];
    const void* b2 = d_in[6];

    char* p = (char*)d_ws;
    auto alloc = [&](size_t bytes) { char* r = p; p += (bytes + 255) & ~(size_t)255; return r; };
    int*   flags    = (int*)alloc(256);
    float* dinv     = (float*)alloc((size_t)N_NODES * 4);
    int*   cnt      = (int*)alloc((size_t)N_NODES * 4);
    int*   rowptr   = (int*)alloc((size_t)(N_NODES + 1) * 4);
    int*   cursor   = (int*)alloc((size_t)N_NODES * 4);
    int*   bsum     = (int*)alloc(256 * 4);
    int*   boff     = (int*)alloc(256 * 4);
    uint2* csr      = (uint2*)alloc((size_t)N_EDGES * 8);
    unsigned short* W1T  = (unsigned short*)alloc((size_t)IN_DIM * HID_DIM * 2);
    unsigned short* W2T  = (unsigned short*)alloc((size_t)HID_DIM * OUT_DIM * 2);
    unsigned short* hbuf = (unsigned short*)alloc((size_t)N_NODES * 128 * 2);
    unsigned short* zbuf = (unsigned short*)alloc((size_t)N_NODES * 128 * 2);

    int nbN = (N_NODES + 255) / 256;
    int nbE = (N_EDGES + 255) / 256;
    int nsb = (N_NODES + SCAN_CHUNK - 1) / SCAN_CHUNK;  // 98

    k_detect<<<1, 256, 0, stream>>>((const unsigned int*)x, (const unsigned int*)ei, flags);
    k_init<<<nbN, 256, 0, stream>>>(cnt, N_NODES);
    k_cnt<<<nbE, 256, 0, stream>>>(ei, flags, cnt, N_EDGES);
    k_scan1<<<nsb, 256, 0, stream>>>(cnt, bsum, N_NODES);
    k_scan2<<<1, 64, 0, stream>>>(bsum, boff, nsb, rowptr, N_NODES);
    k_scan3<<<nsb, 256, 0, stream>>>(cnt, boff, rowptr, cursor, N_NODES);
    k_scatter<<<nbE, 256, 0, stream>>>(ei, ew, flags, cursor, csr, N_EDGES);
    k_degnorm<<<nbN, 256, 0, stream>>>(csr, rowptr, dinv, N_NODES);
    k_norm<<<nbE, 256, 0, stream>>>(csr, dinv, N_EDGES);
    k_transpose<<<(IN_DIM * HID_DIM + HID_DIM * OUT_DIM + 255) / 256, 256, 0, stream>>>(W1, W2, flags, W1T, W2T);

    k_gemm<IN_DIM, true><<<(N_NODES + 63) / 64, 256, 0, stream>>>(x, W1T, hbuf, flags, N_NODES);
    k_aggregate<true, false><<<(N_NODES + 7) / 8, 256, 0, stream>>>(hbuf, rowptr, csr, dinv,
                                                                    b1, zbuf, flags, N_NODES);
    k_gemm<HID_DIM, false><<<(N_NODES + 63) / 64, 256, 0, stream>>>(zbuf, W2T, hbuf, flags, N_NODES);
    k_aggregate<false, true><<<(N_NODES + 7) / 8, 256, 0, stream>>>(hbuf, rowptr, csr, dinv,
                                                                    b2, d_out, flags, N_NODES);
}

// Round 4
// 492.606 us; speedup vs baseline: 1.4946x; 1.2568x over previous
//
#include <hip/hip_runtime.h>
#include <stdint.h>

#define N_NODES 100000
#define N_EDGES 1600000
#define IN_DIM 256
#define HID_DIM 128
#define OUT_DIM 128

#define NBUCK 391        // ceil(100000/256) buckets of 256 nodes
#define CHUNK 4096       // edges per block in bucket passes

typedef __attribute__((ext_vector_type(8))) short short8;
typedef __attribute__((ext_vector_type(4))) float floatx4;

__device__ __forceinline__ float bf2f(unsigned short u) {
    union { unsigned int i; float f; } v; v.i = ((unsigned int)u) << 16; return v.f;
}
__device__ __forceinline__ unsigned short f2bf(float f) {
    union { float fl; unsigned int i; } v; v.fl = f;
    unsigned int x = v.i;
    return (unsigned short)((x + 0x7fffu + ((x >> 16) & 1u)) >> 16);
}
__device__ __forceinline__ float bflo(unsigned int u) {
    union { unsigned int i; float f; } v; v.i = u << 16; return v.f;
}
__device__ __forceinline__ float bfhi(unsigned int u) {
    union { unsigned int i; float f; } v; v.i = u & 0xffff0000u; return v.f;
}
__device__ __forceinline__ float asf(unsigned int u) {
    union { unsigned int i; float f; } v; v.i = u; return v.f;
}
__device__ __forceinline__ unsigned int asu(float f) {
    union { float fl; unsigned int i; } v; v.fl = f; return v.i;
}

// Runtime input-dtype probes: flags[0]=1 if floats are f32 (else bf16); flags[1]=1 if idx i64.
__global__ void k_detect(const unsigned int* __restrict__ xu, const unsigned int* __restrict__ eu,
                         int* __restrict__ flags) {
    __shared__ int s_huge, s_odd;
    if (threadIdx.x == 0) { s_huge = 0; s_odd = 0; }
    __syncthreads();
    int huge = 0, odd = 0;
    for (int i = threadIdx.x; i < 1024; i += 256) {
        unsigned int b = xu[i];
        unsigned int e = (b >> 23) & 0xffu;
        if (e >= 0xf0u) huge = 1;
        if (eu[2 * i + 1] != 0) odd = 1;
    }
    if (huge) atomicOr(&s_huge, 1);
    if (odd) atomicOr(&s_odd, 1);
    __syncthreads();
    if (threadIdx.x == 0) { flags[0] = s_huge ? 0 : 1; flags[1] = s_odd ? 0 : 1; }
}

__device__ __forceinline__ int load_idx(const void* base, long long i, int i64m) {
    int v = i64m ? (int)((const long long*)base)[i] : ((const int*)base)[i];
    return v < 0 ? 0 : (v >= N_NODES ? N_NODES - 1 : v);
}
__device__ __forceinline__ float load_f(const void* base, long long i, int f32m) {
    return f32m ? ((const float*)base)[i] : bf2f(((const unsigned short*)base)[i]);
}

__global__ void k_zero(int* bucket_cnt) {
    int t = threadIdx.x;
    if (t < NBUCK) bucket_cnt[t] = 0;
}

// ---- pass 1: bucket histogram (LDS-aggregated; ~NBUCK atomics per block) ----
__global__ void k_bhist(const void* __restrict__ ei, const int* __restrict__ flags,
                        int* __restrict__ bucket_cnt, int e) {
    __shared__ int h[NBUCK];
    for (int t = threadIdx.x; t < NBUCK; t += 256) h[t] = 0;
    __syncthreads();
    int i64m = flags[1];
    int base = blockIdx.x * CHUNK;
    int end = base + CHUNK < e ? base + CHUNK : e;
    for (int i = base + threadIdx.x; i < end; i += 256) {
        int d = load_idx(ei, (long long)N_EDGES + i, i64m);
        atomicAdd(&h[d >> 8], 1);
    }
    __syncthreads();
    for (int t = threadIdx.x; t < NBUCK; t += 256)
        if (h[t]) atomicAdd(&bucket_cnt[t], h[t]);
}

// ---- pass 2: scan bucket counts -> bases & cursors (1 block) ----
__global__ void k_bscan(const int* __restrict__ bucket_cnt, int* __restrict__ bucket_base,
                        int* __restrict__ bucket_cursor, int* __restrict__ rowptr) {
    __shared__ int lds[512];
    int t = threadIdx.x;
    int v = (t < NBUCK) ? bucket_cnt[t] : 0;
    lds[t] = v;
    __syncthreads();
    for (int off = 1; off < 512; off <<= 1) {
        int x = (t >= off) ? lds[t - off] : 0;
        __syncthreads();
        lds[t] += x;
        __syncthreads();
    }
    int excl = lds[t] - v;
    if (t < NBUCK) { bucket_base[t] = excl; bucket_cursor[t] = excl; }
    if (t == 0) { bucket_base[NBUCK] = lds[NBUCK - 1]; rowptr[N_NODES] = N_EDGES; }
}

// ---- pass 3: bucketed scatter (per-edge LDS atomics; ~NBUCK global atomics/block) ----
__global__ void k_bscatter(const void* __restrict__ ei, const void* __restrict__ ew,
                           const int* __restrict__ flags, int* __restrict__ bucket_cursor,
                           uint2* __restrict__ ebuf, int e) {
    __shared__ int h[NBUCK];
    for (int t = threadIdx.x; t < NBUCK; t += 256) h[t] = 0;
    __syncthreads();
    int f32m = flags[0], i64m = flags[1];
    int base = blockIdx.x * CHUNK;
    int end = base + CHUNK < e ? base + CHUNK : e;
    for (int i = base + threadIdx.x; i < end; i += 256) {
        int d = load_idx(ei, (long long)N_EDGES + i, i64m);
        atomicAdd(&h[d >> 8], 1);
    }
    __syncthreads();
    for (int t = threadIdx.x; t < NBUCK; t += 256) {
        int c = h[t];
        h[t] = c ? atomicAdd(&bucket_cursor[t], c) : 0;  // claim contiguous chunk
    }
    __syncthreads();
    for (int i = base + threadIdx.x; i < end; i += 256) {
        int s = load_idx(ei, i, i64m);
        int d = load_idx(ei, (long long)N_EDGES + i, i64m);
        float w = load_f(ew, i, f32m);
        int b = d >> 8;
        int p = atomicAdd(&h[b], 1);  // LDS cursor holds global position
        uint2 c; c.x = (unsigned int)s | ((unsigned int)(d & 255) << 17); c.y = asu(w);
        ebuf[p] = c;
    }
}

// ---- pass 4: per-bucket fine sort -> final CSR + rowptr + dinv (zero global atomics) ----
__global__ void k_fine(const uint2* __restrict__ ebuf, const int* __restrict__ bucket_base,
                       uint2* __restrict__ csr, int* __restrict__ rowptr,
                       float* __restrict__ dinv, int n) {
    __shared__ int h[256];
    __shared__ float fw[256];
    __shared__ int c2[256];
    int t = threadIdx.x, b = blockIdx.x;
    int e0 = bucket_base[b], e1 = bucket_base[b + 1];
    h[t] = 0; fw[t] = 0.f;
    __syncthreads();
    for (int i = e0 + t; i < e1; i += 256) {
        uint2 c = ebuf[i];
        int dl = (c.x >> 17) & 255;
        atomicAdd(&h[dl], 1);
        atomicAdd(&fw[dl], asf(c.y));
    }
    __syncthreads();
    int own = h[t];
    for (int off = 1; off < 256; off <<= 1) {
        int x = (t >= off) ? h[t - off] : 0;
        __syncthreads();
        h[t] += x;
        __syncthreads();
    }
    int excl = h[t] - own;
    int node = (b << 8) + t;
    if (node < n) {
        rowptr[node] = e0 + excl;
        dinv[node] = rsqrtf(1.0f + fw[t]);  // self-loop weight 1
    }
    c2[t] = e0 + excl;
    __syncthreads();
    for (int i = e0 + t; i < e1; i += 256) {
        uint2 c = ebuf[i];
        int dl = (c.x >> 17) & 255;
        int p = atomicAdd(&c2[dl], 1);
        csr[p] = c;
    }
}

// per-edge: w *= dinv[src]  (coalesced; dinv 400KB L2-resident)
__global__ void k_norm(uint2* __restrict__ csr, const float* __restrict__ dinv, int e) {
    int i = blockIdx.x * 256 + threadIdx.x;
    if (i < e) {
        uint2 c = csr[i];
        csr[i].y = asu(asf(c.y) * dinv[c.x & 0x1FFFF]);
    }
}

// ---------------- weight transpose → bf16 ----------------
__global__ void k_transpose(const void* __restrict__ W1, const void* __restrict__ W2,
                            const int* __restrict__ flags,
                            unsigned short* __restrict__ W1T, unsigned short* __restrict__ W2T) {
    int i = blockIdx.x * 256 + threadIdx.x;
    int f32m = flags[0];
    if (i < IN_DIM * HID_DIM) {
        int k = i / HID_DIM, n = i % HID_DIM;
        W1T[n * IN_DIM + k] = f2bf(load_f(W1, i, f32m));
    } else {
        int j = i - IN_DIM * HID_DIM;
        if (j < HID_DIM * OUT_DIM) {
            int k = j / OUT_DIM, n = j % OUT_DIM;
            W2T[n * HID_DIM + k] = f2bf(load_f(W2, j, f32m));
        }
    }
}

// ---------------- GEMM: H[n,128] = A[n,K] @ W[K,128], MFMA 16x16x32 bf16 ----------------
template <int K, bool RAWA>
__global__ void k_gemm(const void* __restrict__ A, const unsigned short* __restrict__ WT,
                       unsigned short* __restrict__ H, const int* __restrict__ flags, int n) {
    int wave = threadIdx.x >> 6;
    int lane = threadIdx.x & 63;
    int quad = lane >> 4;
    int l16 = lane & 15;
    int rowbase = blockIdx.x * 64 + wave * 16;
    int arow = rowbase + l16;
    if (arow >= n) arow = n - 1;
    int f32m = RAWA ? flags[0] : 0;

    floatx4 acc[8];
#pragma unroll
    for (int c = 0; c < 8; c++) acc[c] = (floatx4){0.f, 0.f, 0.f, 0.f};

#pragma unroll
    for (int k0 = 0; k0 < K; k0 += 32) {
        short8 af;
        if (RAWA && f32m) {
            const float* ap = (const float*)A + (size_t)arow * K + quad * 8 + k0;
            float4 u0 = *(const float4*)ap;
            float4 u1 = *(const float4*)(ap + 4);
            af[0] = (short)f2bf(u0.x); af[1] = (short)f2bf(u0.y);
            af[2] = (short)f2bf(u0.z); af[3] = (short)f2bf(u0.w);
            af[4] = (short)f2bf(u1.x); af[5] = (short)f2bf(u1.y);
            af[6] = (short)f2bf(u1.z); af[7] = (short)f2bf(u1.w);
        } else {
            af = *(const short8*)((const unsigned short*)A + (size_t)arow * K + quad * 8 + k0);
        }
#pragma unroll
        for (int c = 0; c < 8; c++) {
            const unsigned short* bptr = WT + (size_t)(c * 16 + l16) * K + k0 + quad * 8;
            short8 bf = *(const short8*)bptr;
            acc[c] = __builtin_amdgcn_mfma_f32_16x16x32_bf16(af, bf, acc[c], 0, 0, 0);
        }
    }

#pragma unroll
    for (int c = 0; c < 8; c++) {
#pragma unroll
        for (int r = 0; r < 4; r++) {
            int grow = rowbase + quad * 4 + r;
            if (grow < n) H[(size_t)grow * 128 + c * 16 + l16] = f2bf(acc[c][r]);
        }
    }
}

// ---------------- aggregation ----------------
// out[n] = dinv[n]*sum_e (dinv[src]*w)*h[src] + dinv[n]^2*h[n] + b   (opt ReLU)
template <bool RELU, bool FINAL>
__global__ void k_aggregate(const unsigned short* __restrict__ H, const int* __restrict__ rowptr,
                            const uint2* __restrict__ csr, const float* __restrict__ dinv,
                            const void* __restrict__ bias, void* __restrict__ out,
                            const int* __restrict__ flags, int n) {
    int node = blockIdx.x * 8 + (threadIdx.x >> 5);
    int lane = threadIdx.x & 31;
    if (node >= n) return;
    int col = lane * 4;
    int f32m = flags[0];

    float a0 = 0.f, a1 = 0.f, a2 = 0.f, a3 = 0.f;
    int e0 = rowptr[node], e1 = rowptr[node + 1];
    int e = e0;
    for (; e + 2 <= e1; e += 2) {
        uint2 c0 = csr[e], c1 = csr[e + 1];
        uint2 h0 = *(const uint2*)(H + (size_t)(c0.x & 0x1FFFF) * 128 + col);
        uint2 h1 = *(const uint2*)(H + (size_t)(c1.x & 0x1FFFF) * 128 + col);
        float w0 = asf(c0.y), w1 = asf(c1.y);
        a0 += w0 * bflo(h0.x); a1 += w0 * bfhi(h0.x);
        a2 += w0 * bflo(h0.y); a3 += w0 * bfhi(h0.y);
        a0 += w1 * bflo(h1.x); a1 += w1 * bfhi(h1.x);
        a2 += w1 * bflo(h1.y); a3 += w1 * bfhi(h1.y);
    }
    if (e < e1) {
        uint2 c0 = csr[e];
        uint2 h0 = *(const uint2*)(H + (size_t)(c0.x & 0x1FFFF) * 128 + col);
        float w0 = asf(c0.y);
        a0 += w0 * bflo(h0.x); a1 += w0 * bfhi(h0.x);
        a2 += w0 * bflo(h0.y); a3 += w0 * bfhi(h0.y);
    }

    float dn = dinv[node];
    float coef = dn * dn;
    uint2 u = *(const uint2*)(H + (size_t)node * 128 + col);
    a0 = dn * a0 + coef * bflo(u.x) + load_f(bias, col, f32m);
    a1 = dn * a1 + coef * bfhi(u.x) + load_f(bias, col + 1, f32m);
    a2 = dn * a2 + coef * bflo(u.y) + load_f(bias, col + 2, f32m);
    a3 = dn * a3 + coef * bfhi(u.y) + load_f(bias, col + 3, f32m);

    if (RELU) {
        a0 = fmaxf(a0, 0.f); a1 = fmaxf(a1, 0.f);
        a2 = fmaxf(a2, 0.f); a3 = fmaxf(a3, 0.f);
    }
    if (FINAL && f32m) {
        float4 o = {a0, a1, a2, a3};
        *(float4*)((float*)out + (size_t)node * 128 + col) = o;
    } else {
        uint2 o;
        o.x = (unsigned int)f2bf(a0) | ((unsigned int)f2bf(a1) << 16);
        o.y = (unsigned int)f2bf(a2) | ((unsigned int)f2bf(a3) << 16);
        *(uint2*)((unsigned short*)out + (size_t)node * 128 + col) = o;
    }
}

extern "C" void kernel_launch(void* const* d_in, const int* in_sizes, int n_in,
                              void* d_out, int out_size, void* d_ws, size_t ws_size,
                              hipStream_t stream) {
    const void* x  = d_in[0];
    const void* ei = d_in[1];
    const void* ew = d_in[2];
    const void* W1 = d_in[3];
    const void* b1 = d_in[4];
    const void* W2 = d_in[5];
    const void* b2 = d_in[6];

    char* p = (char*)d_ws;
    auto alloc = [&](size_t bytes) { char* r = p; p += (bytes + 255) & ~(size_t)255; return r; };
    int*   flags    = (int*)alloc(256);
    float* dinv     = (float*)alloc((size_t)N_NODES * 4);
    int*   rowptr   = (int*)alloc((size_t)(N_NODES + 1) * 4);
    int*   bucket_cnt    = (int*)alloc((size_t)NBUCK * 4);
    int*   bucket_base   = (int*)alloc((size_t)(NBUCK + 1) * 4);
    int*   bucket_cursor = (int*)alloc((size_t)NBUCK * 4);
    uint2* csr      = (uint2*)alloc((size_t)N_EDGES * 8);
    unsigned short* W1T  = (unsigned short*)alloc((size_t)IN_DIM * HID_DIM * 2);
    unsigned short* W2T  = (unsigned short*)alloc((size_t)HID_DIM * OUT_DIM * 2);
    unsigned short* hbuf = (unsigned short*)alloc((size_t)N_NODES * 128 * 2);
    unsigned short* zbuf = (unsigned short*)alloc((size_t)N_NODES * 128 * 2);
    uint2* ebuf = (uint2*)hbuf;  // alias: ebuf dead before gemm1 writes hbuf (12.8MB < 25.6MB)

    int nbE = (N_EDGES + 255) / 256;
    int nbC = (N_EDGES + CHUNK - 1) / CHUNK;  // 391

    k_detect<<<1, 256, 0, stream>>>((const unsigned int*)x, (const unsigned int*)ei, flags);
    k_zero<<<1, 512, 0, stream>>>(bucket_cnt);
    k_bhist<<<nbC, 256, 0, stream>>>(ei, flags, bucket_cnt, N_EDGES);
    k_bscan<<<1, 512, 0, stream>>>(bucket_cnt, bucket_base, bucket_cursor, rowptr);
    k_bscatter<<<nbC, 256, 0, stream>>>(ei, ew, flags, bucket_cursor, ebuf, N_EDGES);
    k_fine<<<NBUCK, 256, 0, stream>>>(ebuf, bucket_base, csr, rowptr, dinv, N_NODES);
    k_norm<<<nbE, 256, 0, stream>>>(csr, dinv, N_EDGES);
    k_transpose<<<(IN_DIM * HID_DIM + HID_DIM * OUT_DIM + 255) / 256, 256, 0, stream>>>(W1, W2, flags, W1T, W2T);

    k_gemm<IN_DIM, true><<<(N_NODES + 63) / 64, 256, 0, stream>>>(x, W1T, hbuf, flags, N_NODES);
    k_aggregate<true, false><<<(N_NODES + 7) / 8, 256, 0, stream>>>(hbuf, rowptr, csr, dinv,
                                                                    b1, zbuf, flags, N_NODES);
    k_gemm<HID_DIM, false><<<(N_NODES + 63) / 64, 256, 0, stream>>>(zbuf, W2T, hbuf, flags, N_NODES);
    k_aggregate<false, true><<<(N_NODES + 7) / 8, 256, 0, stream>>>(hbuf, rowptr, csr, dinv,
                                                                    b2, d_out, flags, N_NODES);
}

// Round 5
// 437.626 us; speedup vs baseline: 1.6824x; 1.1256x over previous
//
#include <hip/hip_runtime.h>
#include <stdint.h>

#define N_NODES 100000
#define N_EDGES 1600000
#define IN_DIM 256
#define HID_DIM 128
#define OUT_DIM 128

#define NBUCK 391        // ceil(100000/256) buckets of 256 nodes
#define CHUNK 4096       // edges per block in bucket passes

typedef __attribute__((ext_vector_type(8))) short short8;
typedef __attribute__((ext_vector_type(4))) float floatx4;

__device__ __forceinline__ float bf2f(unsigned short u) {
    union { unsigned int i; float f; } v; v.i = ((unsigned int)u) << 16; return v.f;
}
__device__ __forceinline__ unsigned short f2bf(float f) {
    union { float fl; unsigned int i; } v; v.fl = f;
    unsigned int x = v.i;
    return (unsigned short)((x + 0x7fffu + ((x >> 16) & 1u)) >> 16);
}
__device__ __forceinline__ float bflo(unsigned int u) {
    union { unsigned int i; float f; } v; v.i = u << 16; return v.f;
}
__device__ __forceinline__ float bfhi(unsigned int u) {
    union { unsigned int i; float f; } v; v.i = u & 0xffff0000u; return v.f;
}
__device__ __forceinline__ float asf(unsigned int u) {
    union { unsigned int i; float f; } v; v.i = u; return v.f;
}
__device__ __forceinline__ unsigned int asu(float f) {
    union { float fl; unsigned int i; } v; v.fl = f; return v.i;
}
// two f32 -> packed bf16x2 (RNE)
__device__ __forceinline__ unsigned int pack2(float a, float b) {
    unsigned int ua = asu(a), ub = asu(b);
    ua += 0x7fffu + ((ua >> 16) & 1u);
    ub += 0x7fffu + ((ub >> 16) & 1u);
    return (ua >> 16) | (ub & 0xffff0000u);
}
__device__ __forceinline__ short8 pack8(float4 a, float4 b) {
    union { unsigned int u[4]; short8 s; } r;
    r.u[0] = pack2(a.x, a.y);
    r.u[1] = pack2(a.z, a.w);
    r.u[2] = pack2(b.x, b.y);
    r.u[3] = pack2(b.z, b.w);
    return r.s;
}

// Runtime input-dtype probes: flags[0]=1 if floats are f32 (else bf16); flags[1]=1 if idx i64.
// Also zeroes bucket_cnt (folded k_zero).
__global__ void k_detect(const unsigned int* __restrict__ xu, const unsigned int* __restrict__ eu,
                         int* __restrict__ flags, int* __restrict__ bucket_cnt) {
    __shared__ int s_huge, s_odd;
    if (threadIdx.x == 0) { s_huge = 0; s_odd = 0; }
    if (threadIdx.x < NBUCK) bucket_cnt[threadIdx.x] = 0;
    __syncthreads();
    int huge = 0, odd = 0;
    for (int i = threadIdx.x; i < 1024; i += 512) {
        unsigned int b = xu[i];
        unsigned int e = (b >> 23) & 0xffu;
        if (e >= 0xf0u) huge = 1;
        if (eu[2 * i + 1] != 0) odd = 1;
    }
    if (huge) atomicOr(&s_huge, 1);
    if (odd) atomicOr(&s_odd, 1);
    __syncthreads();
    if (threadIdx.x == 0) { flags[0] = s_huge ? 0 : 1; flags[1] = s_odd ? 0 : 1; }
}

__device__ __forceinline__ int load_idx(const void* base, long long i, int i64m) {
    int v = i64m ? (int)((const long long*)base)[i] : ((const int*)base)[i];
    return v < 0 ? 0 : (v >= N_NODES ? N_NODES - 1 : v);
}
__device__ __forceinline__ float load_f(const void* base, long long i, int f32m) {
    return f32m ? ((const float*)base)[i] : bf2f(((const unsigned short*)base)[i]);
}

// ---- pass 1: bucket histogram (LDS-aggregated; ~NBUCK atomics per block) ----
__global__ void k_bhist(const void* __restrict__ ei, const int* __restrict__ flags,
                        int* __restrict__ bucket_cnt, int e) {
    __shared__ int h[NBUCK];
    for (int t = threadIdx.x; t < NBUCK; t += 256) h[t] = 0;
    __syncthreads();
    int i64m = flags[1];
    int base = blockIdx.x * CHUNK;
    int end = base + CHUNK < e ? base + CHUNK : e;
    for (int i = base + threadIdx.x; i < end; i += 256) {
        int d = load_idx(ei, (long long)N_EDGES + i, i64m);
        atomicAdd(&h[d >> 8], 1);
    }
    __syncthreads();
    for (int t = threadIdx.x; t < NBUCK; t += 256)
        if (h[t]) atomicAdd(&bucket_cnt[t], h[t]);
}

// ---- pass 2: scan bucket counts -> bases & cursors (1 block) ----
__global__ void k_bscan(const int* __restrict__ bucket_cnt, int* __restrict__ bucket_base,
                        int* __restrict__ bucket_cursor, int* __restrict__ rowptr) {
    __shared__ int lds[512];
    int t = threadIdx.x;
    int v = (t < NBUCK) ? bucket_cnt[t] : 0;
    lds[t] = v;
    __syncthreads();
    for (int off = 1; off < 512; off <<= 1) {
        int x = (t >= off) ? lds[t - off] : 0;
        __syncthreads();
        lds[t] += x;
        __syncthreads();
    }
    int excl = lds[t] - v;
    if (t < NBUCK) { bucket_base[t] = excl; bucket_cursor[t] = excl; }
    if (t == 0) { bucket_base[NBUCK] = lds[NBUCK - 1]; rowptr[N_NODES] = N_EDGES; }
}

// ---- pass 3: bucketed scatter (per-edge LDS atomics; ~NBUCK global atomics/block) ----
__global__ void k_bscatter(const void* __restrict__ ei, const void* __restrict__ ew,
                           const int* __restrict__ flags, int* __restrict__ bucket_cursor,
                           uint2* __restrict__ ebuf, int e) {
    __shared__ int h[NBUCK];
    for (int t = threadIdx.x; t < NBUCK; t += 256) h[t] = 0;
    __syncthreads();
    int f32m = flags[0], i64m = flags[1];
    int base = blockIdx.x * CHUNK;
    int end = base + CHUNK < e ? base + CHUNK : e;
    for (int i = base + threadIdx.x; i < end; i += 256) {
        int d = load_idx(ei, (long long)N_EDGES + i, i64m);
        atomicAdd(&h[d >> 8], 1);
    }
    __syncthreads();
    for (int t = threadIdx.x; t < NBUCK; t += 256) {
        int c = h[t];
        h[t] = c ? atomicAdd(&bucket_cursor[t], c) : 0;  // claim contiguous chunk
    }
    __syncthreads();
    for (int i = base + threadIdx.x; i < end; i += 256) {
        int s = load_idx(ei, i, i64m);
        int d = load_idx(ei, (long long)N_EDGES + i, i64m);
        float w = load_f(ew, i, f32m);
        int b = d >> 8;
        int p = atomicAdd(&h[b], 1);  // LDS cursor holds global position
        uint2 c; c.x = (unsigned int)s | ((unsigned int)(d & 255) << 17); c.y = asu(w);
        ebuf[p] = c;
    }
}

// ---- pass 4: per-bucket fine sort -> final CSR + rowptr + dinv (zero global atomics) ----
__global__ void k_fine(const uint2* __restrict__ ebuf, const int* __restrict__ bucket_base,
                       uint2* __restrict__ csr, int* __restrict__ rowptr,
                       float* __restrict__ dinv, int n) {
    __shared__ int h[256];
    __shared__ float fw[256];
    __shared__ int c2[256];
    int t = threadIdx.x, b = blockIdx.x;
    int e0 = bucket_base[b], e1 = bucket_base[b + 1];
    h[t] = 0; fw[t] = 0.f;
    __syncthreads();
    for (int i = e0 + t; i < e1; i += 256) {
        uint2 c = ebuf[i];
        int dl = (c.x >> 17) & 255;
        atomicAdd(&h[dl], 1);
        atomicAdd(&fw[dl], asf(c.y));
    }
    __syncthreads();
    int own = h[t];
    for (int off = 1; off < 256; off <<= 1) {
        int x = (t >= off) ? h[t - off] : 0;
        __syncthreads();
        h[t] += x;
        __syncthreads();
    }
    int excl = h[t] - own;
    int node = (b << 8) + t;
    if (node < n) {
        rowptr[node] = e0 + excl;
        dinv[node] = rsqrtf(1.0f + fw[t]);  // self-loop weight 1
    }
    c2[t] = e0 + excl;
    __syncthreads();
    for (int i = e0 + t; i < e1; i += 256) {
        uint2 c = ebuf[i];
        int dl = (c.x >> 17) & 255;
        int p = atomicAdd(&c2[dl], 1);
        csr[p] = c;
    }
}

// per-edge: w *= dinv[src]  (coalesced; dinv 400KB L2-resident)
__global__ void k_norm(uint2* __restrict__ csr, const float* __restrict__ dinv, int e) {
    int i = blockIdx.x * 256 + threadIdx.x;
    if (i < e) {
        uint2 c = csr[i];
        csr[i].y = asu(asf(c.y) * dinv[c.x & 0x1FFFF]);
    }
}

// ---------------- weight transpose → bf16 ----------------
__global__ void k_transpose(const void* __restrict__ W1, const void* __restrict__ W2,
                            const int* __restrict__ flags,
                            unsigned short* __restrict__ W1T, unsigned short* __restrict__ W2T) {
    int i = blockIdx.x * 256 + threadIdx.x;
    int f32m = flags[0];
    if (i < IN_DIM * HID_DIM) {
        int k = i / HID_DIM, n = i % HID_DIM;
        W1T[n * IN_DIM + k] = f2bf(load_f(W1, i, f32m));
    } else {
        int j = i - IN_DIM * HID_DIM;
        if (j < HID_DIM * OUT_DIM) {
            int k = j / OUT_DIM, n = j % OUT_DIM;
            W2T[n * HID_DIM + k] = f2bf(load_f(W2, j, f32m));
        }
    }
}

// ---------------- GEMM: H[n,128] = A[n,K] @ W[K,128], MFMA 16x16x32 bf16 ----------------
// Block: 4 waves, 128 rows. Wave: 32 rows (2 row-tiles of 16) x 128 cols (8 col-tiles).
// B staged in LDS (bf16, [col][K], per-col chunk-rotation swizzle k -> k + (col&7)*8 mod K
// so wave-wide ds_read_b128 hits the optimal 8-lanes-per-4-bank-group pattern, no padding,
// exactly 64KB for K=256). A double-buffered in registers (next chunk's global loads issued
// before current chunk's MFMAs).
template <int K, bool F32M>
__device__ __forceinline__ void gemm_loop(const void* __restrict__ A,
                                          const unsigned short* __restrict__ Bs,
                                          size_t aoff0, size_t aoff1,
                                          int quad, int l16, floatx4 (&acc)[2][8]) {
    constexpr int NCH = K / 32;
    constexpr int BMASK = K / 8 - 1;
    float4 fraw[2][2];
    short8 braw[2];
    if (F32M) {
        const float* ap = (const float*)A;
        fraw[0][0] = *(const float4*)(ap + aoff0);
        fraw[0][1] = *(const float4*)(ap + aoff0 + 4);
        fraw[1][0] = *(const float4*)(ap + aoff1);
        fraw[1][1] = *(const float4*)(ap + aoff1 + 4);
    } else {
        const unsigned short* ap = (const unsigned short*)A;
        braw[0] = *(const short8*)(ap + aoff0);
        braw[1] = *(const short8*)(ap + aoff1);
    }
#pragma unroll
    for (int ch = 0; ch < NCH; ch++) {
        float4 nf[2][2];
        short8 nb[2];
        if (ch + 1 < NCH) {  // issue next chunk's loads before consuming current
            int o = (ch + 1) * 32;
            if (F32M) {
                const float* ap = (const float*)A;
                nf[0][0] = *(const float4*)(ap + aoff0 + o);
                nf[0][1] = *(const float4*)(ap + aoff0 + o + 4);
                nf[1][0] = *(const float4*)(ap + aoff1 + o);
                nf[1][1] = *(const float4*)(ap + aoff1 + o + 4);
            } else {
                const unsigned short* ap = (const unsigned short*)A;
                nb[0] = *(const short8*)(ap + aoff0 + o);
                nb[1] = *(const short8*)(ap + aoff1 + o);
            }
        }
        short8 a0, a1;
        if (F32M) {
            a0 = pack8(fraw[0][0], fraw[0][1]);
            a1 = pack8(fraw[1][0], fraw[1][1]);
        } else {
            a0 = braw[0];
            a1 = braw[1];
        }
#pragma unroll
        for (int c = 0; c < 8; c++) {
            int col = c * 16 + l16;
            int boff = col * K + 8 * ((ch * 4 + quad + (col & 7)) & BMASK);
            short8 bf = *(const short8*)(Bs + boff);
            acc[0][c] = __builtin_amdgcn_mfma_f32_16x16x32_bf16(a0, bf, acc[0][c], 0, 0, 0);
            acc[1][c] = __builtin_amdgcn_mfma_f32_16x16x32_bf16(a1, bf, acc[1][c], 0, 0, 0);
        }
        if (ch + 1 < NCH) {
            if (F32M) {
                fraw[0][0] = nf[0][0]; fraw[0][1] = nf[0][1];
                fraw[1][0] = nf[1][0]; fraw[1][1] = nf[1][1];
            } else {
                braw[0] = nb[0]; braw[1] = nb[1];
            }
        }
    }
}

template <int K, bool RAWA>
__global__ void k_gemm(const void* __restrict__ A, const unsigned short* __restrict__ WT,
                       unsigned short* __restrict__ H, const int* __restrict__ flags, int n) {
    __shared__ unsigned short Bs[128 * K];  // 64KB (K=256) / 32KB (K=128)
    // stage WT -> LDS with per-col chunk-rotation swizzle
    for (int base = threadIdx.x * 8; base < 128 * K; base += 256 * 8) {
        int col = base / K;
        int k = base - col * K;
        int ks = (k + (col & 7) * 8) & (K - 1);
        *(short8*)(&Bs[col * K + ks]) = *(const short8*)(WT + base);
    }
    __syncthreads();

    int wave = threadIdx.x >> 6;
    int lane = threadIdx.x & 63;
    int quad = lane >> 4;
    int l16 = lane & 15;
    int rowbase = blockIdx.x * 128 + wave * 32;
    int r0 = rowbase + l16;        if (r0 >= n) r0 = n - 1;
    int r1 = rowbase + 16 + l16;   if (r1 >= n) r1 = n - 1;
    size_t aoff0 = (size_t)r0 * K + quad * 8;
    size_t aoff1 = (size_t)r1 * K + quad * 8;

    floatx4 acc[2][8];
#pragma unroll
    for (int t = 0; t < 2; t++)
#pragma unroll
        for (int c = 0; c < 8; c++) acc[t][c] = (floatx4){0.f, 0.f, 0.f, 0.f};

    int f32m = RAWA ? flags[0] : 0;
    if (RAWA && f32m)
        gemm_loop<K, true>(A, Bs, aoff0, aoff1, quad, l16, acc);
    else
        gemm_loop<K, false>(A, Bs, aoff0, aoff1, quad, l16, acc);

#pragma unroll
    for (int t = 0; t < 2; t++)
#pragma unroll
        for (int c = 0; c < 8; c++)
#pragma unroll
            for (int r = 0; r < 4; r++) {
                int grow = rowbase + t * 16 + quad * 4 + r;
                if (grow < n) H[(size_t)grow * 128 + c * 16 + l16] = f2bf(acc[t][c][r]);
            }
}

// ---------------- aggregation ----------------
// out[n] = dinv[n]*sum_e (dinv[src]*w)*h[src] + dinv[n]^2*h[n] + b   (opt ReLU)
// 8 nodes x 32 lanes per block; lane covers 4 consecutive cols; edge loop unrolled x4.
template <bool RELU, bool FINAL>
__global__ void k_aggregate(const unsigned short* __restrict__ H, const int* __restrict__ rowptr,
                            const uint2* __restrict__ csr, const float* __restrict__ dinv,
                            const void* __restrict__ bias, void* __restrict__ out,
                            const int* __restrict__ flags, int n) {
    int node = blockIdx.x * 8 + (threadIdx.x >> 5);
    int lane = threadIdx.x & 31;
    if (node >= n) return;
    int col = lane * 4;
    int f32m = flags[0];

    float a0 = 0.f, a1 = 0.f, a2 = 0.f, a3 = 0.f;
    int e0 = rowptr[node], e1 = rowptr[node + 1];
    int e = e0;
    for (; e + 4 <= e1; e += 4) {
        uint2 c0 = csr[e], c1 = csr[e + 1], c2 = csr[e + 2], c3 = csr[e + 3];
        uint2 h0 = *(const uint2*)(H + (size_t)(c0.x & 0x1FFFF) * 128 + col);
        uint2 h1 = *(const uint2*)(H + (size_t)(c1.x & 0x1FFFF) * 128 + col);
        uint2 h2 = *(const uint2*)(H + (size_t)(c2.x & 0x1FFFF) * 128 + col);
        uint2 h3 = *(const uint2*)(H + (size_t)(c3.x & 0x1FFFF) * 128 + col);
        float w0 = asf(c0.y), w1 = asf(c1.y), w2 = asf(c2.y), w3 = asf(c3.y);
        a0 += w0 * bflo(h0.x); a1 += w0 * bfhi(h0.x); a2 += w0 * bflo(h0.y); a3 += w0 * bfhi(h0.y);
        a0 += w1 * bflo(h1.x); a1 += w1 * bfhi(h1.x); a2 += w1 * bflo(h1.y); a3 += w1 * bfhi(h1.y);
        a0 += w2 * bflo(h2.x); a1 += w2 * bfhi(h2.x); a2 += w2 * bflo(h2.y); a3 += w2 * bfhi(h2.y);
        a0 += w3 * bflo(h3.x); a1 += w3 * bfhi(h3.x); a2 += w3 * bflo(h3.y); a3 += w3 * bfhi(h3.y);
    }
    for (; e < e1; e++) {
        uint2 c0 = csr[e];
        uint2 h0 = *(const uint2*)(H + (size_t)(c0.x & 0x1FFFF) * 128 + col);
        float w0 = asf(c0.y);
        a0 += w0 * bflo(h0.x); a1 += w0 * bfhi(h0.x);
        a2 += w0 * bflo(h0.y); a3 += w0 * bfhi(h0.y);
    }

    float dn = dinv[node];
    float coef = dn * dn;
    uint2 u = *(const uint2*)(H + (size_t)node * 128 + col);
    a0 = dn * a0 + coef * bflo(u.x) + load_f(bias, col, f32m);
    a1 = dn * a1 + coef * bfhi(u.x) + load_f(bias, col + 1, f32m);
    a2 = dn * a2 + coef * bflo(u.y) + load_f(bias, col + 2, f32m);
    a3 = dn * a3 + coef * bfhi(u.y) + load_f(bias, col + 3, f32m);

    if (RELU) {
        a0 = fmaxf(a0, 0.f); a1 = fmaxf(a1, 0.f);
        a2 = fmaxf(a2, 0.f); a3 = fmaxf(a3, 0.f);
    }
    if (FINAL && f32m) {
        float4 o = {a0, a1, a2, a3};
        *(float4*)((float*)out + (size_t)node * 128 + col) = o;
    } else {
        uint2 o;
        o.x = (unsigned int)f2bf(a0) | ((unsigned int)f2bf(a1) << 16);
        o.y = (unsigned int)f2bf(a2) | ((unsigned int)f2bf(a3) << 16);
        *(uint2*)((unsigned short*)out + (size_t)node * 128 + col) = o;
    }
}

extern "C" void kernel_launch(void* const* d_in, const int* in_sizes, int n_in,
                              void* d_out, int out_size, void* d_ws, size_t ws_size,
                              hipStream_t stream) {
    const void* x  = d_in[0];
    const void* ei = d_in[1];
    const void* ew = d_in[2];
    const void* W1 = d_in[3];
    const void* b1 = d_in[4];
    const void* W2 = d_in[5];
    const void* b2 = d_in[6];

    char* p = (char*)d_ws;
    auto alloc = [&](size_t bytes) { char* r = p; p += (bytes + 255) & ~(size_t)255; return r; };
    int*   flags    = (int*)alloc(256);
    float* dinv     = (float*)alloc((size_t)N_NODES * 4);
    int*   rowptr   = (int*)alloc((size_t)(N_NODES + 1) * 4);
    int*   bucket_cnt    = (int*)alloc((size_t)NBUCK * 4);
    int*   bucket_base   = (int*)alloc((size_t)(NBUCK + 1) * 4);
    int*   bucket_cursor = (int*)alloc((size_t)NBUCK * 4);
    uint2* csr      = (uint2*)alloc((size_t)N_EDGES * 8);
    unsigned short* W1T  = (unsigned short*)alloc((size_t)IN_DIM * HID_DIM * 2);
    unsigned short* W2T  = (unsigned short*)alloc((size_t)HID_DIM * OUT_DIM * 2);
    unsigned short* hbuf = (unsigned short*)alloc((size_t)N_NODES * 128 * 2);
    unsigned short* zbuf = (unsigned short*)alloc((size_t)N_NODES * 128 * 2);
    uint2* ebuf = (uint2*)hbuf;  // alias: ebuf dead before gemm1 writes hbuf

    int nbE = (N_EDGES + 255) / 256;
    int nbC = (N_EDGES + CHUNK - 1) / CHUNK;  // 391
    int nbG = (N_NODES + 127) / 128;          // 782

    k_detect<<<1, 512, 0, stream>>>((const unsigned int*)x, (const unsigned int*)ei, flags, bucket_cnt);
    k_bhist<<<nbC, 256, 0, stream>>>(ei, flags, bucket_cnt, N_EDGES);
    k_bscan<<<1, 512, 0, stream>>>(bucket_cnt, bucket_base, bucket_cursor, rowptr);
    k_bscatter<<<nbC, 256, 0, stream>>>(ei, ew, flags, bucket_cursor, ebuf, N_EDGES);
    k_fine<<<NBUCK, 256, 0, stream>>>(ebuf, bucket_base, csr, rowptr, dinv, N_NODES);
    k_norm<<<nbE, 256, 0, stream>>>(csr, dinv, N_EDGES);
    k_transpose<<<(IN_DIM * HID_DIM + HID_DIM * OUT_DIM + 255) / 256, 256, 0, stream>>>(W1, W2, flags, W1T, W2T);

    k_gemm<IN_DIM, true><<<nbG, 256, 0, stream>>>(x, W1T, hbuf, flags, N_NODES);
    k_aggregate<true, false><<<(N_NODES + 7) / 8, 256, 0, stream>>>(hbuf, rowptr, csr, dinv,
                                                                    b1, zbuf, flags, N_NODES);
    k_gemm<HID_DIM, false><<<nbG, 256, 0, stream>>>(zbuf, W2T, hbuf, flags, N_NODES);
    k_aggregate<false, true><<<(N_NODES + 7) / 8, 256, 0, stream>>>(hbuf, rowptr, csr, dinv,
                                                                    b2, d_out, flags, N_NODES);
}

// Round 6
// 434.659 us; speedup vs baseline: 1.6939x; 1.0068x over previous
//
#include <hip/hip_runtime.h>
#include <stdint.h>

#define N_NODES 100000
#define N_EDGES 1600000
#define IN_DIM 256
#define HID_DIM 128
#define OUT_DIM 128

#define NBUCK 391        // ceil(100000/256) buckets of 256 nodes
#define CHUNK 4096       // edges per block in bucket passes

typedef __attribute__((ext_vector_type(8))) short short8;
typedef __attribute__((ext_vector_type(4))) float floatx4;

__device__ __forceinline__ float bf2f(unsigned short u) {
    union { unsigned int i; float f; } v; v.i = ((unsigned int)u) << 16; return v.f;
}
__device__ __forceinline__ unsigned short f2bf(float f) {
    union { float fl; unsigned int i; } v; v.fl = f;
    unsigned int x = v.i;
    return (unsigned short)((x + 0x7fffu + ((x >> 16) & 1u)) >> 16);
}
__device__ __forceinline__ float bflo(unsigned int u) {
    union { unsigned int i; float f; } v; v.i = u << 16; return v.f;
}
__device__ __forceinline__ float bfhi(unsigned int u) {
    union { unsigned int i; float f; } v; v.i = u & 0xffff0000u; return v.f;
}
__device__ __forceinline__ float asf(unsigned int u) {
    union { unsigned int i; float f; } v; v.i = u; return v.f;
}
__device__ __forceinline__ unsigned int asu(float f) {
    union { float fl; unsigned int i; } v; v.fl = f; return v.i;
}
// two f32 -> packed bf16x2 (RNE)
__device__ __forceinline__ unsigned int pack2(float a, float b) {
    unsigned int ua = asu(a), ub = asu(b);
    ua += 0x7fffu + ((ua >> 16) & 1u);
    ub += 0x7fffu + ((ub >> 16) & 1u);
    return (ua >> 16) | (ub & 0xffff0000u);
}
__device__ __forceinline__ short8 pack8(float4 a, float4 b) {
    union { unsigned int u[4]; short8 s; } r;
    r.u[0] = pack2(a.x, a.y);
    r.u[1] = pack2(a.z, a.w);
    r.u[2] = pack2(b.x, b.y);
    r.u[3] = pack2(b.z, b.w);
    return r.s;
}

// Runtime input-dtype probes: flags[0]=1 if floats are f32 (else bf16); flags[1]=1 if idx i64.
// Also zeroes bucket_cnt (folded k_zero).
__global__ void k_detect(const unsigned int* __restrict__ xu, const unsigned int* __restrict__ eu,
                         int* __restrict__ flags, int* __restrict__ bucket_cnt) {
    __shared__ int s_huge, s_odd;
    if (threadIdx.x == 0) { s_huge = 0; s_odd = 0; }
    if (threadIdx.x < NBUCK) bucket_cnt[threadIdx.x] = 0;
    __syncthreads();
    int huge = 0, odd = 0;
    for (int i = threadIdx.x; i < 1024; i += 512) {
        unsigned int b = xu[i];
        unsigned int e = (b >> 23) & 0xffu;
        if (e >= 0xf0u) huge = 1;
        if (eu[2 * i + 1] != 0) odd = 1;
    }
    if (huge) atomicOr(&s_huge, 1);
    if (odd) atomicOr(&s_odd, 1);
    __syncthreads();
    if (threadIdx.x == 0) { flags[0] = s_huge ? 0 : 1; flags[1] = s_odd ? 0 : 1; }
}

__device__ __forceinline__ int load_idx(const void* base, long long i, int i64m) {
    int v = i64m ? (int)((const long long*)base)[i] : ((const int*)base)[i];
    return v < 0 ? 0 : (v >= N_NODES ? N_NODES - 1 : v);
}
__device__ __forceinline__ float load_f(const void* base, long long i, int f32m) {
    return f32m ? ((const float*)base)[i] : bf2f(((const unsigned short*)base)[i]);
}

// ---- pass 1: bucket histogram (LDS-aggregated; ~NBUCK atomics per block) ----
__global__ void k_bhist(const void* __restrict__ ei, const int* __restrict__ flags,
                        int* __restrict__ bucket_cnt, int e) {
    __shared__ int h[NBUCK];
    for (int t = threadIdx.x; t < NBUCK; t += 256) h[t] = 0;
    __syncthreads();
    int i64m = flags[1];
    int base = blockIdx.x * CHUNK;
    int end = base + CHUNK < e ? base + CHUNK : e;
    for (int i = base + threadIdx.x; i < end; i += 256) {
        int d = load_idx(ei, (long long)N_EDGES + i, i64m);
        atomicAdd(&h[d >> 8], 1);
    }
    __syncthreads();
    for (int t = threadIdx.x; t < NBUCK; t += 256)
        if (h[t]) atomicAdd(&bucket_cnt[t], h[t]);
}

// ---- pass 2: scan bucket counts -> bases & cursors (1 block) ----
__global__ void k_bscan(const int* __restrict__ bucket_cnt, int* __restrict__ bucket_base,
                        int* __restrict__ bucket_cursor, int* __restrict__ rowptr) {
    __shared__ int lds[512];
    int t = threadIdx.x;
    int v = (t < NBUCK) ? bucket_cnt[t] : 0;
    lds[t] = v;
    __syncthreads();
    for (int off = 1; off < 512; off <<= 1) {
        int x = (t >= off) ? lds[t - off] : 0;
        __syncthreads();
        lds[t] += x;
        __syncthreads();
    }
    int excl = lds[t] - v;
    if (t < NBUCK) { bucket_base[t] = excl; bucket_cursor[t] = excl; }
    if (t == 0) { bucket_base[NBUCK] = lds[NBUCK - 1]; rowptr[N_NODES] = N_EDGES; }
}

// ---- pass 3: bucketed scatter (per-edge LDS atomics; ~NBUCK global atomics/block) ----
__global__ void k_bscatter(const void* __restrict__ ei, const void* __restrict__ ew,
                           const int* __restrict__ flags, int* __restrict__ bucket_cursor,
                           uint2* __restrict__ ebuf, int e) {
    __shared__ int h[NBUCK];
    for (int t = threadIdx.x; t < NBUCK; t += 256) h[t] = 0;
    __syncthreads();
    int f32m = flags[0], i64m = flags[1];
    int base = blockIdx.x * CHUNK;
    int end = base + CHUNK < e ? base + CHUNK : e;
    for (int i = base + threadIdx.x; i < end; i += 256) {
        int d = load_idx(ei, (long long)N_EDGES + i, i64m);
        atomicAdd(&h[d >> 8], 1);
    }
    __syncthreads();
    for (int t = threadIdx.x; t < NBUCK; t += 256) {
        int c = h[t];
        h[t] = c ? atomicAdd(&bucket_cursor[t], c) : 0;  // claim contiguous chunk
    }
    __syncthreads();
    for (int i = base + threadIdx.x; i < end; i += 256) {
        int s = load_idx(ei, i, i64m);
        int d = load_idx(ei, (long long)N_EDGES + i, i64m);
        float w = load_f(ew, i, f32m);
        int b = d >> 8;
        int p = atomicAdd(&h[b], 1);  // LDS cursor holds global position
        uint2 c; c.x = (unsigned int)s | ((unsigned int)(d & 255) << 17); c.y = asu(w);
        ebuf[p] = c;
    }
}

// ---- pass 4: per-bucket fine sort -> final CSR + rowptr + dinv (zero global atomics) ----
__global__ void k_fine(const uint2* __restrict__ ebuf, const int* __restrict__ bucket_base,
                       uint2* __restrict__ csr, int* __restrict__ rowptr,
                       float* __restrict__ dinv, int n) {
    __shared__ int h[256];
    __shared__ float fw[256];
    __shared__ int c2[256];
    int t = threadIdx.x, b = blockIdx.x;
    int e0 = bucket_base[b], e1 = bucket_base[b + 1];
    h[t] = 0; fw[t] = 0.f;
    __syncthreads();
    for (int i = e0 + t; i < e1; i += 256) {
        uint2 c = ebuf[i];
        int dl = (c.x >> 17) & 255;
        atomicAdd(&h[dl], 1);
        atomicAdd(&fw[dl], asf(c.y));
    }
    __syncthreads();
    int own = h[t];
    for (int off = 1; off < 256; off <<= 1) {
        int x = (t >= off) ? h[t - off] : 0;
        __syncthreads();
        h[t] += x;
        __syncthreads();
    }
    int excl = h[t] - own;
    int node = (b << 8) + t;
    if (node < n) {
        rowptr[node] = e0 + excl;
        dinv[node] = rsqrtf(1.0f + fw[t]);  // self-loop weight 1
    }
    c2[t] = e0 + excl;
    __syncthreads();
    for (int i = e0 + t; i < e1; i += 256) {
        uint2 c = ebuf[i];
        int dl = (c.x >> 17) & 255;
        int p = atomicAdd(&c2[dl], 1);
        csr[p] = c;
    }
}

// ---------------- weight transpose → bf16 ----------------
__global__ void k_transpose(const void* __restrict__ W1, const void* __restrict__ W2,
                            const int* __restrict__ flags,
                            unsigned short* __restrict__ W1T, unsigned short* __restrict__ W2T) {
    int i = blockIdx.x * 256 + threadIdx.x;
    int f32m = flags[0];
    if (i < IN_DIM * HID_DIM) {
        int k = i / HID_DIM, n = i % HID_DIM;
        W1T[n * IN_DIM + k] = f2bf(load_f(W1, i, f32m));
    } else {
        int j = i - IN_DIM * HID_DIM;
        if (j < HID_DIM * OUT_DIM) {
            int k = j / OUT_DIM, n = j % OUT_DIM;
            W2T[n * HID_DIM + k] = f2bf(load_f(W2, j, f32m));
        }
    }
}

// ---------------- GEMM: H[n,128] = A[n,K] @ W[K,128], MFMA 16x16x32 bf16 ----------------
// Block: 4 waves, 128 rows. Wave: 32 rows (2 row-tiles of 16) x 128 cols (8 col-tiles).
// B staged in LDS with per-col chunk-rotation swizzle; A register double-buffered.
template <int K, bool F32M>
__device__ __forceinline__ void gemm_loop(const void* __restrict__ A,
                                          const unsigned short* __restrict__ Bs,
                                          size_t aoff0, size_t aoff1,
                                          int quad, int l16, floatx4 (&acc)[2][8]) {
    constexpr int NCH = K / 32;
    constexpr int BMASK = K / 8 - 1;
    float4 fraw[2][2];
    short8 braw[2];
    if (F32M) {
        const float* ap = (const float*)A;
        fraw[0][0] = *(const float4*)(ap + aoff0);
        fraw[0][1] = *(const float4*)(ap + aoff0 + 4);
        fraw[1][0] = *(const float4*)(ap + aoff1);
        fraw[1][1] = *(const float4*)(ap + aoff1 + 4);
    } else {
        const unsigned short* ap = (const unsigned short*)A;
        braw[0] = *(const short8*)(ap + aoff0);
        braw[1] = *(const short8*)(ap + aoff1);
    }
#pragma unroll
    for (int ch = 0; ch < NCH; ch++) {
        float4 nf[2][2];
        short8 nb[2];
        if (ch + 1 < NCH) {  // issue next chunk's loads before consuming current
            int o = (ch + 1) * 32;
            if (F32M) {
                const float* ap = (const float*)A;
                nf[0][0] = *(const float4*)(ap + aoff0 + o);
                nf[0][1] = *(const float4*)(ap + aoff0 + o + 4);
                nf[1][0] = *(const float4*)(ap + aoff1 + o);
                nf[1][1] = *(const float4*)(ap + aoff1 + o + 4);
            } else {
                const unsigned short* ap = (const unsigned short*)A;
                nb[0] = *(const short8*)(ap + aoff0 + o);
                nb[1] = *(const short8*)(ap + aoff1 + o);
            }
        }
        short8 a0, a1;
        if (F32M) {
            a0 = pack8(fraw[0][0], fraw[0][1]);
            a1 = pack8(fraw[1][0], fraw[1][1]);
        } else {
            a0 = braw[0];
            a1 = braw[1];
        }
#pragma unroll
        for (int c = 0; c < 8; c++) {
            int col = c * 16 + l16;
            int boff = col * K + 8 * ((ch * 4 + quad + (col & 7)) & BMASK);
            short8 bf = *(const short8*)(Bs + boff);
            acc[0][c] = __builtin_amdgcn_mfma_f32_16x16x32_bf16(a0, bf, acc[0][c], 0, 0, 0);
            acc[1][c] = __builtin_amdgcn_mfma_f32_16x16x32_bf16(a1, bf, acc[1][c], 0, 0, 0);
        }
        if (ch + 1 < NCH) {
            if (F32M) {
                fraw[0][0] = nf[0][0]; fraw[0][1] = nf[0][1];
                fraw[1][0] = nf[1][0]; fraw[1][1] = nf[1][1];
            } else {
                braw[0] = nb[0]; braw[1] = nb[1];
            }
        }
    }
}

template <int K, bool RAWA>
__global__ void k_gemm(const void* __restrict__ A, const unsigned short* __restrict__ WT,
                       unsigned short* __restrict__ H, const int* __restrict__ flags, int n) {
    __shared__ unsigned short Bs[128 * K];  // 64KB (K=256) / 32KB (K=128)
    for (int base = threadIdx.x * 8; base < 128 * K; base += 256 * 8) {
        int col = base / K;
        int k = base - col * K;
        int ks = (k + (col & 7) * 8) & (K - 1);
        *(short8*)(&Bs[col * K + ks]) = *(const short8*)(WT + base);
    }
    __syncthreads();

    int wave = threadIdx.x >> 6;
    int lane = threadIdx.x & 63;
    int quad = lane >> 4;
    int l16 = lane & 15;
    int rowbase = blockIdx.x * 128 + wave * 32;
    int r0 = rowbase + l16;        if (r0 >= n) r0 = n - 1;
    int r1 = rowbase + 16 + l16;   if (r1 >= n) r1 = n - 1;
    size_t aoff0 = (size_t)r0 * K + quad * 8;
    size_t aoff1 = (size_t)r1 * K + quad * 8;

    floatx4 acc[2][8];
#pragma unroll
    for (int t = 0; t < 2; t++)
#pragma unroll
        for (int c = 0; c < 8; c++) acc[t][c] = (floatx4){0.f, 0.f, 0.f, 0.f};

    int f32m = RAWA ? flags[0] : 0;
    if (RAWA && f32m)
        gemm_loop<K, true>(A, Bs, aoff0, aoff1, quad, l16, acc);
    else
        gemm_loop<K, false>(A, Bs, aoff0, aoff1, quad, l16, acc);

#pragma unroll
    for (int t = 0; t < 2; t++)
#pragma unroll
        for (int c = 0; c < 8; c++)
#pragma unroll
            for (int r = 0; r < 4; r++) {
                int grow = rowbase + t * 16 + quad * 4 + r;
                if (grow < n) H[(size_t)grow * 128 + c * 16 + l16] = f2bf(acc[t][c][r]);
            }
}

// ---------------- aggregation ----------------
// out[n] = dinv[n]*sum_e (w*dinv[src])*h[src] + dinv[n]^2*h[n] + b   (opt ReLU)
// 16 nodes x 16 lanes per block; lane covers 8 cols (one dwordx4 gather per edge);
// dinv[src] gathered in-loop (L2-resident, 400KB) — k_norm pass eliminated.
template <bool RELU, bool FINAL>
__global__ void k_aggregate(const unsigned short* __restrict__ H, const int* __restrict__ rowptr,
                            const uint2* __restrict__ csr, const float* __restrict__ dinv,
                            const void* __restrict__ bias, void* __restrict__ out,
                            const int* __restrict__ flags, int n) {
    int node = blockIdx.x * 16 + (threadIdx.x >> 4);
    int lane = threadIdx.x & 15;
    if (node >= n) return;
    int col = lane * 8;
    int f32m = flags[0];

    float a0 = 0.f, a1 = 0.f, a2 = 0.f, a3 = 0.f;
    float a4 = 0.f, a5 = 0.f, a6 = 0.f, a7 = 0.f;
    int e0 = rowptr[node], e1 = rowptr[node + 1];
    int e = e0;
    for (; e + 4 <= e1; e += 4) {
        uint2 c0 = csr[e], c1 = csr[e + 1], c2 = csr[e + 2], c3 = csr[e + 3];
        int s0 = c0.x & 0x1FFFF, s1 = c1.x & 0x1FFFF, s2 = c2.x & 0x1FFFF, s3 = c3.x & 0x1FFFF;
        uint4 h0 = *(const uint4*)(H + (size_t)s0 * 128 + col);
        uint4 h1 = *(const uint4*)(H + (size_t)s1 * 128 + col);
        uint4 h2 = *(const uint4*)(H + (size_t)s2 * 128 + col);
        uint4 h3 = *(const uint4*)(H + (size_t)s3 * 128 + col);
        float w0 = asf(c0.y) * dinv[s0], w1 = asf(c1.y) * dinv[s1];
        float w2 = asf(c2.y) * dinv[s2], w3 = asf(c3.y) * dinv[s3];
        a0 += w0 * bflo(h0.x); a1 += w0 * bfhi(h0.x); a2 += w0 * bflo(h0.y); a3 += w0 * bfhi(h0.y);
        a4 += w0 * bflo(h0.z); a5 += w0 * bfhi(h0.z); a6 += w0 * bflo(h0.w); a7 += w0 * bfhi(h0.w);
        a0 += w1 * bflo(h1.x); a1 += w1 * bfhi(h1.x); a2 += w1 * bflo(h1.y); a3 += w1 * bfhi(h1.y);
        a4 += w1 * bflo(h1.z); a5 += w1 * bfhi(h1.z); a6 += w1 * bflo(h1.w); a7 += w1 * bfhi(h1.w);
        a0 += w2 * bflo(h2.x); a1 += w2 * bfhi(h2.x); a2 += w2 * bflo(h2.y); a3 += w2 * bfhi(h2.y);
        a4 += w2 * bflo(h2.z); a5 += w2 * bfhi(h2.z); a6 += w2 * bflo(h2.w); a7 += w2 * bfhi(h2.w);
        a0 += w3 * bflo(h3.x); a1 += w3 * bfhi(h3.x); a2 += w3 * bflo(h3.y); a3 += w3 * bfhi(h3.y);
        a4 += w3 * bflo(h3.z); a5 += w3 * bfhi(h3.z); a6 += w3 * bflo(h3.w); a7 += w3 * bfhi(h3.w);
    }
    for (; e < e1; e++) {
        uint2 c0 = csr[e];
        int s0 = c0.x & 0x1FFFF;
        uint4 h0 = *(const uint4*)(H + (size_t)s0 * 128 + col);
        float w0 = asf(c0.y) * dinv[s0];
        a0 += w0 * bflo(h0.x); a1 += w0 * bfhi(h0.x); a2 += w0 * bflo(h0.y); a3 += w0 * bfhi(h0.y);
        a4 += w0 * bflo(h0.z); a5 += w0 * bfhi(h0.z); a6 += w0 * bflo(h0.w); a7 += w0 * bfhi(h0.w);
    }

    float dn = dinv[node];
    float coef = dn * dn;
    uint4 u = *(const uint4*)(H + (size_t)node * 128 + col);
    a0 = dn * a0 + coef * bflo(u.x) + load_f(bias, col, f32m);
    a1 = dn * a1 + coef * bfhi(u.x) + load_f(bias, col + 1, f32m);
    a2 = dn * a2 + coef * bflo(u.y) + load_f(bias, col + 2, f32m);
    a3 = dn * a3 + coef * bfhi(u.y) + load_f(bias, col + 3, f32m);
    a4 = dn * a4 + coef * bflo(u.z) + load_f(bias, col + 4, f32m);
    a5 = dn * a5 + coef * bfhi(u.z) + load_f(bias, col + 5, f32m);
    a6 = dn * a6 + coef * bflo(u.w) + load_f(bias, col + 6, f32m);
    a7 = dn * a7 + coef * bfhi(u.w) + load_f(bias, col + 7, f32m);

    if (RELU) {
        a0 = fmaxf(a0, 0.f); a1 = fmaxf(a1, 0.f); a2 = fmaxf(a2, 0.f); a3 = fmaxf(a3, 0.f);
        a4 = fmaxf(a4, 0.f); a5 = fmaxf(a5, 0.f); a6 = fmaxf(a6, 0.f); a7 = fmaxf(a7, 0.f);
    }
    if (FINAL && f32m) {
        float* op = (float*)out + (size_t)node * 128 + col;
        float4 o0 = {a0, a1, a2, a3};
        float4 o1 = {a4, a5, a6, a7};
        *(float4*)op = o0;
        *(float4*)(op + 4) = o1;
    } else {
        uint4 o;
        o.x = pack2(a0, a1); o.y = pack2(a2, a3);
        o.z = pack2(a4, a5); o.w = pack2(a6, a7);
        *(uint4*)((unsigned short*)out + (size_t)node * 128 + col) = o;
    }
}

extern "C" void kernel_launch(void* const* d_in, const int* in_sizes, int n_in,
                              void* d_out, int out_size, void* d_ws, size_t ws_size,
                              hipStream_t stream) {
    const void* x  = d_in[0];
    const void* ei = d_in[1];
    const void* ew = d_in[2];
    const void* W1 = d_in[3];
    const void* b1 = d_in[4];
    const void* W2 = d_in[5];
    const void* b2 = d_in[6];

    char* p = (char*)d_ws;
    auto alloc = [&](size_t bytes) { char* r = p; p += (bytes + 255) & ~(size_t)255; return r; };
    int*   flags    = (int*)alloc(256);
    float* dinv     = (float*)alloc((size_t)N_NODES * 4);
    int*   rowptr   = (int*)alloc((size_t)(N_NODES + 1) * 4);
    int*   bucket_cnt    = (int*)alloc((size_t)NBUCK * 4);
    int*   bucket_base   = (int*)alloc((size_t)(NBUCK + 1) * 4);
    int*   bucket_cursor = (int*)alloc((size_t)NBUCK * 4);
    uint2* csr      = (uint2*)alloc((size_t)N_EDGES * 8);
    unsigned short* W1T  = (unsigned short*)alloc((size_t)IN_DIM * HID_DIM * 2);
    unsigned short* W2T  = (unsigned short*)alloc((size_t)HID_DIM * OUT_DIM * 2);
    unsigned short* hbuf = (unsigned short*)alloc((size_t)N_NODES * 128 * 2);
    unsigned short* zbuf = (unsigned short*)alloc((size_t)N_NODES * 128 * 2);
    uint2* ebuf = (uint2*)hbuf;  // alias: ebuf dead before gemm1 writes hbuf

    int nbC = (N_EDGES + CHUNK - 1) / CHUNK;  // 391
    int nbG = (N_NODES + 127) / 128;          // 782
    int nbA = (N_NODES + 15) / 16;            // 6250

    k_detect<<<1, 512, 0, stream>>>((const unsigned int*)x, (const unsigned int*)ei, flags, bucket_cnt);
    k_bhist<<<nbC, 256, 0, stream>>>(ei, flags, bucket_cnt, N_EDGES);
    k_bscan<<<1, 512, 0, stream>>>(bucket_cnt, bucket_base, bucket_cursor, rowptr);
    k_bscatter<<<nbC, 256, 0, stream>>>(ei, ew, flags, bucket_cursor, ebuf, N_EDGES);
    k_fine<<<NBUCK, 256, 0, stream>>>(ebuf, bucket_base, csr, rowptr, dinv, N_NODES);
    k_transpose<<<(IN_DIM * HID_DIM + HID_DIM * OUT_DIM + 255) / 256, 256, 0, stream>>>(W1, W2, flags, W1T, W2T);

    k_gemm<IN_DIM, true><<<nbG, 256, 0, stream>>>(x, W1T, hbuf, flags, N_NODES);
    k_aggregate<true, false><<<nbA, 256, 0, stream>>>(hbuf, rowptr, csr, dinv,
                                                      b1, zbuf, flags, N_NODES);
    k_gemm<HID_DIM, false><<<nbG, 256, 0, stream>>>(zbuf, W2T, hbuf, flags, N_NODES);
    k_aggregate<false, true><<<nbA, 256, 0, stream>>>(hbuf, rowptr, csr, dinv,
                                                      b2, d_out, flags, N_NODES);
}